// Round 15
// baseline (130.479 us; speedup 1.0000x reference)
//
#include <hip/hip_runtime.h>
#include <stdint.h>

static constexpr int B_ = 512, N_ = 32, D_ = 256, K_ = 8;
static constexpr int E1 = 40, E2 = 6;          // ee MLP dims 256->40->6->1
static constexpr int N1 = 81, N2 = 25, N3 = 8; // en MLP dims 256->81->25->8
static constexpr int XBP = 264;                // xs_h row stride (f16): 132 dw -> 2-way
static constexpr int HEP = 104;                // h1e row stride (f16): 52 dw -> 2-way
static constexpr int EWT = 264;                // ew1T row stride (f16)
static constexpr int TKP = 40;                 // en tile k-stride (f16): 20 dw -> 2-way
static constexpr int NWP = 104;                // nw2T row stride (f16): 52 dw -> 2-way
static constexpr int TILE16 = 16 * TKP;       // per-wave en tile, f16 elems (1280 B)
static constexpr float LN2f  = 0.69314718055994530942f;
static constexpr float L2Ef  = 1.44269504088896340736f;

typedef float    f32x4 __attribute__((ext_vector_type(4)));
typedef _Float16 f16x8 __attribute__((ext_vector_type(8)));
typedef _Float16 f16x4 __attribute__((ext_vector_type(4)));

#if __has_builtin(__builtin_amdgcn_mfma_f32_16x16x16_f16)
#define MFMA16(A, B, C) __builtin_amdgcn_mfma_f32_16x16x16_f16((A), (B), (C), 0, 0, 0)
#else
#define MFMA16(A, B, C) __builtin_amdgcn_mfma_f32_16x16x16f16((A), (B), (C), 0, 0, 0)
#endif

// base-2 shifted softplus: returns ssp(x)/ln2 where t = x*log2e.
__device__ __forceinline__ float ssp2(float t) {
    float e = __builtin_amdgcn_exp2f(t);
    return __builtin_amdgcn_logf(fmaf(e, 0.5f, 0.5f));   // v_log_f32 = log2
}

// ee epilogue: act -> MFMA16 layer2 -> act -> layer3 -> allreduce -> contract
#define EE_EPI(ACC, I)                                                         \
    {                                                                          \
        const float rix = rs_s[(I) * 3 + 0], riy = rs_s[(I) * 3 + 1],          \
                    riz = rs_s[(I) * 3 + 2];                                   \
        float cxi = 0.f, cyi = 0.f, czi = 0.f;                                 \
        _Pragma("unroll")                                                      \
        for (int h = 0; h < 2; ++h) {                                          \
            f32x4 acc2 = b2i;                                                  \
            _Pragma("unroll")                                                  \
            for (int Nt = 0; Nt < 3; ++Nt) {                                   \
                f16x4 bh;                                                      \
                _Pragma("unroll")                                              \
                for (int r2 = 0; r2 < 4; ++r2)                                 \
                    bh[r2] = (_Float16)ssp2(ACC[h][Nt][r2]);                   \
                acc2 = MFMA16(b2fT[Nt], bh, acc2);                             \
            }                                                                  \
            float ws = 0.f;                                                    \
            _Pragma("unroll")                                                  \
            for (int r2 = 0; r2 < 4; ++r2)                                     \
                ws = fmaf(w3q[r2], ssp2(acc2[r2]), ws);                        \
            ws += __shfl_xor(ws, 16);                                          \
            ws += __shfl_xor(ws, 32);                                          \
            float wj = ws + eb3v;                                              \
            int j = c + 16 * h;                                                \
            cxi = fmaf(wj, rix - rs_s[j * 3 + 0], cxi);                        \
            cyi = fmaf(wj, riy - rs_s[j * 3 + 1], cyi);                        \
            czi = fmaf(wj, riz - rs_s[j * 3 + 2], czi);                        \
        }                                                                      \
        _Pragma("unroll")                                                      \
        for (int m2 = 1; m2 < 16; m2 <<= 1) {                                  \
            cxi += __shfl_xor(cxi, m2);                                        \
            cyi += __shfl_xor(cyi, m2);                                        \
            czi += __shfl_xor(czi, m2);                                        \
        }                                                                      \
        if (l == 0) {                                                          \
            bfe_s[(I) * 3 + 0] = cxi;                                          \
            bfe_s[(I) * 3 + 1] = cyi;                                          \
            bfe_s[(I) * 3 + 2] = czi;                                          \
        }                                                                      \
    }

// single fused kernel; grid = B_ (one block per batch), 512 threads (8 waves)
// NOTE: no occupancy arg in launch_bounds (R10: pinning forced VGPR<=64 and
// spilled everything; allocator floats to ~124 = 2 blocks/CU).
__global__ __launch_bounds__(512) void k_fused(
    const float* __restrict__ rs, const float* __restrict__ xs,
    const float* __restrict__ coords,
    const float* __restrict__ ew1, const float* __restrict__ eb1,
    const float* __restrict__ ew2, const float* __restrict__ eb2,
    const float* __restrict__ ew3, const float* __restrict__ eb3,
    const float* __restrict__ nw1, const float* __restrict__ nb1,
    const float* __restrict__ nw2, const float* __restrict__ nb2,
    const float* __restrict__ nw3, const float* __restrict__ nb3,
    float* __restrict__ out)
{
    __shared__ alignas(16) _Float16 xs_h[N_ * XBP];    // 16896 B
    __shared__ alignas(16) _Float16 wbuf[48 * EWT];    // 25344 B: ew1T (*log2e), rows 40..47 zero
    // uni (17664 B), en phase:
    //   [0,7680)      6 per-wave nw1 tiles (1280 B each) -> then nw2T (6656 B)
    //   [7680,14336)  h1e f16 [32][HEP=104]
    //   [14336,17664) h2e f32 [32][26]
    __shared__ alignas(16) char uni[17664];
    __shared__ float nw3_s[N2 * N3];
    __shared__ float rs_s[N_ * 3];
    __shared__ float nb2_s[N2];
    __shared__ float nb3_s[N3];
    __shared__ float co_s[K_ * 3];
    __shared__ float bfn_s[N_ * 3];
    __shared__ float cut_s[N_];
    __shared__ float bfe_s[N_ * 3];
    __shared__ alignas(16) float eb1_s[48];            // eb1*log2e, padded
    __shared__ alignas(16) float b2_s[16];             // eb2*log2e, padded

    _Float16* h1e  = (_Float16*)(uni + 7680);          // [32][HEP]
    float*    h2e  = (float*)(uni + 14336);            // [32][26]
    _Float16* nw2T = (_Float16*)uni;                   // [32][NWP] (en L2 phase)

    const int b = blockIdx.x, t = threadIdx.x;
    const int wv = t >> 6, l = t & 63, quad = l >> 4, c = l & 15;

    // ---- static per-lane constants ----
    // ee W2^T as MFMA16 A-frags: A[m=c][k=quad*4+r] per Nt = W2[n=16Nt+quad*4+r][m=c]
    f16x4 b2fT[3];
    #pragma unroll
    for (int Nt = 0; Nt < 3; ++Nt) {
        f16x4 p;
        #pragma unroll
        for (int r = 0; r < 4; ++r) {
            int n = Nt * 16 + quad * 4 + r;
            p[r] = (_Float16)((n < E1 && c < E2) ? ew2[n * E2 + c] : 0.f);
        }
        b2fT[Nt] = p;
    }
    float w3q[4];   // w3*ln2 by row m=quad*4+r
    #pragma unroll
    for (int r = 0; r < 4; ++r) {
        int m = quad * 4 + r;
        w3q[r] = (m < E2) ? ew3[m] * LN2f : 0.f;
    }
    const float eb3v = eb3[0];

    // ---- stage xs[b] fp32 -> fp16 LDS ----
    {
        const float4* src = (const float4*)(xs + (size_t)b * N_ * D_);
        #pragma unroll
        for (int u = 0; u < 4; ++u) {
            int q = t + 512 * u;              // 2048 float4
            float4 v = src[q];
            int row = q >> 6, col4 = q & 63;
            union { _Float16 h[4]; uint64_t u64; } pk;
            pk.h[0] = (_Float16)v.x; pk.h[1] = (_Float16)v.y;
            pk.h[2] = (_Float16)v.z; pk.h[3] = (_Float16)v.w;
            *(uint64_t*)&xs_h[row * XBP + col4 * 4] = pk.u64;
        }
    }
    // ---- stage ew1*log2e [256][40] -> ew1T [40 n][264 k] f16 (transposed) ----
    {
        const float4* src = (const float4*)ew1;   // 2560 float4
        #pragma unroll
        for (int u = 0; u < 5; ++u) {
            int q = t + 512 * u;
            float4 v = src[q];
            int k = q / 10, n0 = (q - 10 * k) * 4;
            wbuf[(n0 + 0) * EWT + k] = (_Float16)(v.x * L2Ef);
            wbuf[(n0 + 1) * EWT + k] = (_Float16)(v.y * L2Ef);
            wbuf[(n0 + 2) * EWT + k] = (_Float16)(v.z * L2Ef);
            wbuf[(n0 + 3) * EWT + k] = (_Float16)(v.w * L2Ef);
        }
    }
    // zero ew1T pad rows 40..47 (read as A-operand in ee main; must be finite)
    {
        uint32_t* z = (uint32_t*)(wbuf + 40 * EWT);   // 1056 dwords
        #pragma unroll
        for (int u = 0; u < 3; ++u) {
            int idx = t + 512 * u;
            if (idx < 1056) z[idx] = 0u;
        }
    }
    // zero h1e cols 80..95 (layer-2 K-pad; col 80 rewritten by wave 5)
    if (t < 128) {
        int m = t >> 2, q4 = t & 3;
        *(uint64_t*)(uni + 7680 + m * (HEP * 2) + 160 + q4 * 8) = 0ull;
    }
    if (t < N_ * 3) rs_s[t] = rs[b * N_ * 3 + t];
    if (t < N2 * N3) nw3_s[t] = nw3[t] * LN2f;
    if (t < N2) nb2_s[t] = nb2[t] * L2Ef;
    if (t < N3) nb3_s[t] = nb3[t];
    if (t < K_ * 3) co_s[t] = coords[t];
    if (t < 48) eb1_s[t] = (t < E1) ? eb1[t] * L2Ef : 0.f;
    if (t < 16) b2_s[t] = (t < E2) ? eb2[t] * L2Ef : 0.f;
    __syncthreads();   // B1: xs_h + ew1T(+pad) + h1e-pad + misc ready

    // ---- en layer 1: wave wv<6 owns Nt=wv (both Mt), private tile, NO barriers
    if (wv < 6) {
        _Float16* tile = (_Float16*)uni + wv * TILE16;   // [16 n][TKP k]
        const int ln = l & 15, lq = l >> 4;
        const int gn = wv * 16 + ln;                     // staged col (n)
        const bool gok = (gn < N1);
        const int n_col = wv * 16 + c;                   // MFMA col (n)
        const float nb1v = (n_col < N1) ? nb1[n_col] * L2Ef : 0.f;

        float pf[8];
        #pragma unroll
        for (int u = 0; u < 8; ++u)
            pf[u] = gok ? nw1[(lq + 4 * u) * N1 + gn] : 0.f;

        f32x4 acc[2];
        acc[0] = (f32x4){0.f, 0.f, 0.f, 0.f};
        acc[1] = (f32x4){0.f, 0.f, 0.f, 0.f};

        #pragma unroll 1
        for (int Kt = 0; Kt < 8; ++Kt) {
            #pragma unroll
            for (int u = 0; u < 8; ++u)
                tile[ln * TKP + lq + 4 * u] = (_Float16)(pf[u] * L2Ef);
            if (Kt < 7) {
                const float* wk = nw1 + (Kt + 1) * 32 * N1 + gn;
                #pragma unroll
                for (int u = 0; u < 8; ++u)
                    pf[u] = gok ? wk[(lq + 4 * u) * N1] : 0.f;
            }
            // same-wave RAW: compiler inserts lgkmcnt before this read
            f16x8 Bf = *(const f16x8*)&tile[c * TKP + quad * 8];
            #pragma unroll
            for (int Mt = 0; Mt < 2; ++Mt) {
                f16x8 A = *(const f16x8*)&xs_h[(Mt * 16 + c) * XBP + Kt * 32 + quad * 8];
                acc[Mt] = __builtin_amdgcn_mfma_f32_16x16x32_f16(A, Bf, acc[Mt], 0, 0, 0);
            }
        }
        if (n_col < N1) {
            #pragma unroll
            for (int Mt = 0; Mt < 2; ++Mt)
                #pragma unroll
                for (int r2 = 0; r2 < 4; ++r2) {
                    int m = Mt * 16 + quad * 4 + r2;
                    h1e[m * HEP + n_col] = (_Float16)ssp2(acc[Mt][r2] + nb1v);
                }
        }
    }
    __syncthreads();   // B3: h1e done, tiles dead

    // ---- stage nw2T [32 n][NWP k] f16 into dead tile region ----
    #pragma unroll
    for (int u = 0; u < 6; ++u) {
        int idx = t + 512 * u;                // 3072 = 32 n x 96 kk
        int n = idx / 96, kk = idx - 96 * n;
        float v = (kk < N1 && n < N2) ? nw2[kk * N2 + n] : 0.f;
        nw2T[n * NWP + kk] = (_Float16)v;
    }
    __syncthreads();   // B5: nw2T ready

    // ---- en layer 2 via MFMA (waves 0..3): h2 = ssp2(h1e @ nw2 + nb2') ----
    if (wv < 4) {
        const int Mt = wv & 1, Nt = wv >> 1;
        f32x4 acc2 = {0.f, 0.f, 0.f, 0.f};
        #pragma unroll
        for (int Kt2 = 0; Kt2 < 3; ++Kt2) {
            f16x8 A  = *(const f16x8*)&h1e[(Mt * 16 + c) * HEP + Kt2 * 32 + quad * 8];
            f16x8 Bf = *(const f16x8*)&nw2T[(Nt * 16 + c) * NWP + Kt2 * 32 + quad * 8];
            acc2 = __builtin_amdgcn_mfma_f32_16x16x32_f16(A, Bf, acc2, 0, 0, 0);
        }
        int n = Nt * 16 + c;
        if (n < N2) {
            #pragma unroll
            for (int r2 = 0; r2 < 4; ++r2) {
                int m = Mt * 16 + quad * 4 + r2;
                h2e[m * 26 + n] = ssp2(acc2[r2] + nb2_s[n]);
            }
        }
    }
    __syncthreads();   // B6: h2e complete

    // ---- en layer 3 + bf_nuc + cutoff (threads 0..255; waves 4-7 fall through
    //      into ee main and overlap this) ----
    if (t < 256) {
        const int r = t >> 3, s = t & 7;
        float w = nb3_s[s];
        const int rb = r * 26;
        #pragma unroll
        for (int kk = 0; kk < N2; ++kk)
            w = fmaf(h2e[rb + kk], nw3_s[kk * N3 + s], w);

        float dx = rs_s[r * 3 + 0] - co_s[s * 3 + 0];
        float dy = rs_s[r * 3 + 1] - co_s[s * 3 + 1];
        float dz = rs_s[r * 3 + 2] - co_s[s * 3 + 2];
        float cx = w * dx, cy = w * dy, cz = w * dz;
        #pragma unroll
        for (int m2 = 1; m2 < 8; m2 <<= 1) {
            cx += __shfl_xor(cx, m2);
            cy += __shfl_xor(cy, m2);
            cz += __shfl_xor(cz, m2);
        }
        float rr  = sqrtf(dx * dx + dy * dy + dz * dz);
        float xsc = 2.f * rr;                 // r / L, L = 0.5
        float cf  = (xsc < 0.5f) ? xsc * xsc * (6.f - 8.f * xsc + 3.f * xsc * xsc) : 1.f;
        #pragma unroll
        for (int m2 = 1; m2 < 8; m2 <<= 1) cf *= __shfl_xor(cf, m2);
        if (s == 0) {
            bfn_s[r * 3 + 0] = cx;
            bfn_s[r * 3 + 1] = cy;
            bfn_s[r * 3 + 2] = cz;
            cut_s[r] = cf;
        }
    }
    // no barrier: bfn_s/cut_s only read after B8 below

    // ---- ee main: paired i per pass (iA = wv+16p, iB = iA+8) ----
    // Layer-1: D = W1'^T (A, from LDS) x P (B) -> h1^T C-layout [n][j=c], which
    // is the 16x16x16 B-operand layout -> layer-2 straight from registers.
    // Pairing: 12 indep MFMA chains in K-loop, 2 indep epilogues (ILP), and
    // jv0/jv1 LDS reads amortized over both i.
    const f32x4 b2i = *(const f32x4*)&b2_s[quad * 4];
    #pragma unroll 1
    for (int p = 0; p < 2; ++p) {
        const int iA = wv + 16 * p, iB = iA + 8;
        f32x4 accA[2][3], accB[2][3];
        #pragma unroll
        for (int Nt = 0; Nt < 3; ++Nt) {
            f32x4 bias = *(const f32x4*)&eb1_s[Nt * 16 + quad * 4];
            accA[0][Nt] = bias; accA[1][Nt] = bias;
            accB[0][Nt] = bias; accB[1][Nt] = bias;
        }

        #pragma unroll
        for (int Kt = 0; Kt < 8; ++Kt) {
            const int koff = Kt * 32 + quad * 8;
            f16x8 jv0 = *(const f16x8*)&xs_h[c * XBP + koff];
            f16x8 jv1 = *(const f16x8*)&xs_h[(16 + c) * XBP + koff];
            f16x8 ivA = *(const f16x8*)&xs_h[iA * XBP + koff];
            f16x8 ivB = *(const f16x8*)&xs_h[iB * XBP + koff];
            f16x8 PA0 = ivA * jv0, PA1 = ivA * jv1;
            f16x8 PB0 = ivB * jv0, PB1 = ivB * jv1;
            #pragma unroll
            for (int Nt = 0; Nt < 3; ++Nt) {
                f16x8 Af = *(const f16x8*)&wbuf[(Nt * 16 + c) * EWT + koff];
                accA[0][Nt] = __builtin_amdgcn_mfma_f32_16x16x32_f16(Af, PA0, accA[0][Nt], 0, 0, 0);
                accA[1][Nt] = __builtin_amdgcn_mfma_f32_16x16x32_f16(Af, PA1, accA[1][Nt], 0, 0, 0);
                accB[0][Nt] = __builtin_amdgcn_mfma_f32_16x16x32_f16(Af, PB0, accB[0][Nt], 0, 0, 0);
                accB[1][Nt] = __builtin_amdgcn_mfma_f32_16x16x32_f16(Af, PB1, accB[1][Nt], 0, 0, 0);
            }
        }
        EE_EPI(accA, iA)
        EE_EPI(accB, iB)
    }
    __syncthreads();   // B8: bfe_s (+ bfn_s/cut_s) ready

    // ---- final combine + store (threads 0..95) ----
    if (t < N_ * 3) {
        int i = t / 3;
        out[(size_t)b * (N_ * 3) + t] =
            rs_s[t] + 1e-4f * cut_s[i] * (bfe_s[t] + bfn_s[t]);
    }
}

extern "C" void kernel_launch(void* const* d_in, const int* in_sizes, int n_in,
                              void* d_out, int out_size, void* d_ws, size_t ws_size,
                              hipStream_t stream)
{
    const float* rs     = (const float*)d_in[0];
    const float* xs     = (const float*)d_in[1];
    const float* coords = (const float*)d_in[2];
    const float* ew1    = (const float*)d_in[3];
    const float* eb1    = (const float*)d_in[4];
    const float* ew2    = (const float*)d_in[5];
    const float* eb2    = (const float*)d_in[6];
    const float* ew3    = (const float*)d_in[7];
    const float* eb3    = (const float*)d_in[8];
    const float* nw1    = (const float*)d_in[9];
    const float* nb1    = (const float*)d_in[10];
    const float* nw2    = (const float*)d_in[11];
    const float* nb2    = (const float*)d_in[12];
    const float* nw3    = (const float*)d_in[13];
    const float* nb3    = (const float*)d_in[14];

    k_fused<<<B_, 512, 0, stream>>>(rs, xs, coords, ew1, eb1, ew2, eb2, ew3, eb3,
                                    nw1, nb1, nw2, nb2, nw3, nb3, (float*)d_out);
}

// Round 16
// 127.782 us; speedup vs baseline: 1.0211x; 1.0211x over previous
//
#include <hip/hip_runtime.h>
#include <stdint.h>

static constexpr int B_ = 512, N_ = 32, D_ = 256, K_ = 8;
static constexpr int E1 = 40, E2 = 6;          // ee MLP dims 256->40->6->1
static constexpr int N1 = 81, N2 = 25, N3 = 8; // en MLP dims 256->81->25->8
static constexpr int XBP = 264;                // xs_h row stride (f16): 132 dw -> 2-way
static constexpr int HEP = 104;                // h1e row stride (f16): 52 dw -> 2-way
static constexpr int EWT = 264;                // ew1T row stride (f16)
static constexpr int TKP = 40;                 // en tile k-stride (f16): 80 B, 16B-aligned
static constexpr int NWP = 104;                // nw2T row stride (f16): 52 dw -> 2-way
static constexpr int TILE16 = 16 * TKP;       // per-wave en tile, f16 elems (1280 B)
static constexpr float LN2f  = 0.69314718055994530942f;
static constexpr float L2Ef  = 1.44269504088896340736f;

typedef float    f32x4 __attribute__((ext_vector_type(4)));
typedef _Float16 f16x8 __attribute__((ext_vector_type(8)));
typedef _Float16 f16x4 __attribute__((ext_vector_type(4)));

#if __has_builtin(__builtin_amdgcn_mfma_f32_16x16x16_f16)
#define MFMA16(A, B, C) __builtin_amdgcn_mfma_f32_16x16x16_f16((A), (B), (C), 0, 0, 0)
#else
#define MFMA16(A, B, C) __builtin_amdgcn_mfma_f32_16x16x16f16((A), (B), (C), 0, 0, 0)
#endif

// base-2 shifted softplus: returns ssp(x)/ln2 where t = x*log2e.
// Weights/biases are pre-scaled so inputs arrive as t and the ln2 output
// scale is folded into the next layer's weights (ln2*log2e = 1 keeps W2 raw).
__device__ __forceinline__ float ssp2(float t) {
    float e = __builtin_amdgcn_exp2f(t);
    return __builtin_amdgcn_logf(fmaf(e, 0.5f, 0.5f));   // v_log_f32 = log2
}

// single fused kernel; grid = B_ (one block per batch), 512 threads (8 waves)
// NOTE: no occupancy arg in launch_bounds (R10/R15: pinning or over-pressuring
// spills; allocator floats to ~124 = 2 blocks/CU). Keep live VGPRs <= ~124.
__global__ __launch_bounds__(512) void k_fused(
    const float* __restrict__ rs, const float* __restrict__ xs,
    const float* __restrict__ coords,
    const float* __restrict__ ew1, const float* __restrict__ eb1,
    const float* __restrict__ ew2, const float* __restrict__ eb2,
    const float* __restrict__ ew3, const float* __restrict__ eb3,
    const float* __restrict__ nw1, const float* __restrict__ nb1,
    const float* __restrict__ nw2, const float* __restrict__ nb2,
    const float* __restrict__ nw3, const float* __restrict__ nb3,
    float* __restrict__ out)
{
    __shared__ alignas(16) _Float16 xs_h[N_ * XBP];    // 16896 B
    __shared__ alignas(16) _Float16 wbuf[E1 * EWT];    // 21120 B: ew1T (*log2e)
    // uni (17664 B), en phase:
    //   [0,7680)      6 per-wave nw1 tiles (1280 B each) -> then nw2T (6656 B)
    //   [7680,14336)  h1e f16 [32][HEP=104]
    //   [14336,17664) h2e f32 [32][26]
    __shared__ alignas(16) char uni[17664];
    __shared__ float nw3_s[N2 * N3];
    __shared__ float rs_s[N_ * 3];
    __shared__ float nb2_s[N2];
    __shared__ float nb3_s[N3];
    __shared__ float co_s[K_ * 3];
    __shared__ float bfn_s[N_ * 3];
    __shared__ float cut_s[N_];
    __shared__ float bfe_s[N_ * 3];
    __shared__ alignas(16) float eb1_s[48];            // eb1*log2e, padded
    __shared__ alignas(16) float b2_s[16];             // eb2*log2e, padded

    _Float16* h1e  = (_Float16*)(uni + 7680);          // [32][HEP]
    float*    h2e  = (float*)(uni + 14336);            // [32][26]
    _Float16* nw2T = (_Float16*)uni;                   // [32][NWP] (en L2 phase)

    const int b = blockIdx.x, t = threadIdx.x;
    const int wv = t >> 6, l = t & 63, quad = l >> 4, c = l & 15;

    // ---- static per-lane constants ----
    // ee W2^T as MFMA16 A-frags: A[m=c][k=quad*4+r] per Nt = W2[n=16Nt+quad*4+r][m=c]
    f16x4 b2fT[3];
    #pragma unroll
    for (int Nt = 0; Nt < 3; ++Nt) {
        f16x4 p;
        #pragma unroll
        for (int r = 0; r < 4; ++r) {
            int n = Nt * 16 + quad * 4 + r;
            p[r] = (_Float16)((n < E1 && c < E2) ? ew2[n * E2 + c] : 0.f);
        }
        b2fT[Nt] = p;
    }
    float w3q[4];   // w3*ln2 by row m=quad*4+r
    #pragma unroll
    for (int r = 0; r < 4; ++r) {
        int m = quad * 4 + r;
        w3q[r] = (m < E2) ? ew3[m] * LN2f : 0.f;
    }
    const float eb3v = eb3[0];

    // ---- stage xs[b] fp32 -> fp16 LDS ----
    {
        const float4* src = (const float4*)(xs + (size_t)b * N_ * D_);
        #pragma unroll
        for (int u = 0; u < 4; ++u) {
            int q = t + 512 * u;              // 2048 float4
            float4 v = src[q];
            int row = q >> 6, col4 = q & 63;
            union { _Float16 h[4]; uint64_t u64; } pk;
            pk.h[0] = (_Float16)v.x; pk.h[1] = (_Float16)v.y;
            pk.h[2] = (_Float16)v.z; pk.h[3] = (_Float16)v.w;
            *(uint64_t*)&xs_h[row * XBP + col4 * 4] = pk.u64;
        }
    }
    // ---- stage ew1*log2e [256][40] -> ew1T [40 n][264 k] f16 (transposed) ----
    {
        const float4* src = (const float4*)ew1;   // 2560 float4
        #pragma unroll
        for (int u = 0; u < 5; ++u) {
            int q = t + 512 * u;
            float4 v = src[q];
            int k = q / 10, n0 = (q - 10 * k) * 4;
            wbuf[(n0 + 0) * EWT + k] = (_Float16)(v.x * L2Ef);
            wbuf[(n0 + 1) * EWT + k] = (_Float16)(v.y * L2Ef);
            wbuf[(n0 + 2) * EWT + k] = (_Float16)(v.z * L2Ef);
            wbuf[(n0 + 3) * EWT + k] = (_Float16)(v.w * L2Ef);
        }
    }
    // zero h1e cols 80..95 (layer-2 K-pad; col 80 rewritten by wave 5)
    if (t < 128) {
        int m = t >> 2, q4 = t & 3;
        *(uint64_t*)(uni + 7680 + m * (HEP * 2) + 160 + q4 * 8) = 0ull;
    }
    if (t < N_ * 3) rs_s[t] = rs[b * N_ * 3 + t];
    if (t < N2 * N3) nw3_s[t] = nw3[t] * LN2f;
    if (t < N2) nb2_s[t] = nb2[t] * L2Ef;
    if (t < N3) nb3_s[t] = nb3[t];
    if (t < K_ * 3) co_s[t] = coords[t];
    if (t < 48) eb1_s[t] = (t < E1) ? eb1[t] * L2Ef : 0.f;
    if (t < 16) b2_s[t] = (t < E2) ? eb2[t] * L2Ef : 0.f;
    __syncthreads();   // B1: xs_h + ew1T + h1e-pad + misc ready

    // ---- en layer 1: wave wv<6 owns Nt=wv (both Mt), private tile, NO barriers
    // lane (ln,lq) owns k = 8*lq..8*lq+7 (contiguous) -> ONE ds_write_b128/Kt
    if (wv < 6) {
        _Float16* tile = (_Float16*)uni + wv * TILE16;   // [16 n][TKP k]
        const int ln = l & 15, lq = l >> 4;
        const int gn = wv * 16 + ln;                     // staged col (n)
        const bool gok = (gn < N1);
        const int n_col = wv * 16 + c;                   // MFMA col (n)
        const float nb1v = (n_col < N1) ? nb1[n_col] * L2Ef : 0.f;

        float pf[8];
        #pragma unroll
        for (int u = 0; u < 8; ++u)
            pf[u] = gok ? nw1[(lq * 8 + u) * N1 + gn] : 0.f;

        f32x4 acc[2];
        acc[0] = (f32x4){0.f, 0.f, 0.f, 0.f};
        acc[1] = (f32x4){0.f, 0.f, 0.f, 0.f};

        #pragma unroll 1
        for (int Kt = 0; Kt < 8; ++Kt) {
            f16x8 pk;
            #pragma unroll
            for (int u = 0; u < 8; ++u)
                pk[u] = (_Float16)(pf[u] * L2Ef);
            *(f16x8*)&tile[ln * TKP + lq * 8] = pk;      // single b128 store
            if (Kt < 7) {
                const float* wk = nw1 + (Kt + 1) * 32 * N1 + gn;
                #pragma unroll
                for (int u = 0; u < 8; ++u)
                    pf[u] = gok ? wk[(lq * 8 + u) * N1] : 0.f;
            }
            // same-wave RAW: compiler inserts lgkmcnt before this read
            f16x8 Bf = *(const f16x8*)&tile[c * TKP + quad * 8];
            #pragma unroll
            for (int Mt = 0; Mt < 2; ++Mt) {
                f16x8 A = *(const f16x8*)&xs_h[(Mt * 16 + c) * XBP + Kt * 32 + quad * 8];
                acc[Mt] = __builtin_amdgcn_mfma_f32_16x16x32_f16(A, Bf, acc[Mt], 0, 0, 0);
            }
        }
        if (n_col < N1) {
            #pragma unroll
            for (int Mt = 0; Mt < 2; ++Mt)
                #pragma unroll
                for (int r2 = 0; r2 < 4; ++r2) {
                    int m = Mt * 16 + quad * 4 + r2;
                    h1e[m * HEP + n_col] = (_Float16)ssp2(acc[Mt][r2] + nb1v);
                }
        }
    }
    __syncthreads();   // B3: h1e done, tiles dead, ew1T still intact

    // ---- build ee W1^T A-frags from ew1T (24 ds_read_b128 per lane) ----
    // A-layout: lane(quad,c) holds A[n=c+16Nt][k=quad*8+d+32Kt].
    f16x8 b1f[3][8];
    #pragma unroll
    for (int Nt = 0; Nt < 3; ++Nt) {
        int n = Nt * 16 + c;
        bool ok = (n < E1);
        int row = ok ? n : 0;
        #pragma unroll
        for (int Kt = 0; Kt < 8; ++Kt) {
            f16x8 v = *(const f16x8*)&wbuf[row * EWT + Kt * 32 + quad * 8];
            if (!ok) v = (f16x8)(_Float16)0.f;
            b1f[Nt][Kt] = v;
        }
    }
    // ---- stage nw2T [32 n][NWP k] f16 into dead tile region ----
    #pragma unroll
    for (int u = 0; u < 6; ++u) {
        int idx = t + 512 * u;                // 3072 = 32 n x 96 kk
        int n = idx / 96, kk = idx - 96 * n;
        float v = (kk < N1 && n < N2) ? nw2[kk * N2 + n] : 0.f;
        nw2T[n * NWP + kk] = (_Float16)v;
    }
    __syncthreads();   // B5: nw2T ready (b1f reads of wbuf also done)

    // ---- en layer 2 via MFMA (waves 0..3): h2 = ssp2(h1e @ nw2 + nb2') ----
    if (wv < 4) {
        const int Mt = wv & 1, Nt = wv >> 1;
        f32x4 acc2 = {0.f, 0.f, 0.f, 0.f};
        #pragma unroll
        for (int Kt2 = 0; Kt2 < 3; ++Kt2) {
            f16x8 A  = *(const f16x8*)&h1e[(Mt * 16 + c) * HEP + Kt2 * 32 + quad * 8];
            f16x8 Bf = *(const f16x8*)&nw2T[(Nt * 16 + c) * NWP + Kt2 * 32 + quad * 8];
            acc2 = __builtin_amdgcn_mfma_f32_16x16x32_f16(A, Bf, acc2, 0, 0, 0);
        }
        int n = Nt * 16 + c;
        if (n < N2) {
            #pragma unroll
            for (int r2 = 0; r2 < 4; ++r2) {
                int m = Mt * 16 + quad * 4 + r2;
                h2e[m * 26 + n] = ssp2(acc2[r2] + nb2_s[n]);
            }
        }
    }
    __syncthreads();   // B6: h2e complete

    // ---- en layer 3 + bf_nuc + cutoff (threads 0..255; waves 4-7 fall through
    //      into ee main and overlap this) ----
    if (t < 256) {
        const int r = t >> 3, s = t & 7;
        float w = nb3_s[s];
        const int rb = r * 26;
        #pragma unroll
        for (int kk = 0; kk < N2; ++kk)
            w = fmaf(h2e[rb + kk], nw3_s[kk * N3 + s], w);

        float dx = rs_s[r * 3 + 0] - co_s[s * 3 + 0];
        float dy = rs_s[r * 3 + 1] - co_s[s * 3 + 1];
        float dz = rs_s[r * 3 + 2] - co_s[s * 3 + 2];
        float cx = w * dx, cy = w * dy, cz = w * dz;
        #pragma unroll
        for (int m2 = 1; m2 < 8; m2 <<= 1) {
            cx += __shfl_xor(cx, m2);
            cy += __shfl_xor(cy, m2);
            cz += __shfl_xor(cz, m2);
        }
        float rr  = sqrtf(dx * dx + dy * dy + dz * dz);
        float xsc = 2.f * rr;                 // r / L, L = 0.5
        float cf  = (xsc < 0.5f) ? xsc * xsc * (6.f - 8.f * xsc + 3.f * xsc * xsc) : 1.f;
        #pragma unroll
        for (int m2 = 1; m2 < 8; m2 <<= 1) cf *= __shfl_xor(cf, m2);
        if (s == 0) {
            bfn_s[r * 3 + 0] = cx;
            bfn_s[r * 3 + 1] = cy;
            bfn_s[r * 3 + 2] = cz;
            cut_s[r] = cf;
        }
    }
    // no barrier: bfn_s/cut_s only read after B8 below

    // ---- ee main: 4 i per wave; h=0/1 -> j=0..15 / 16..31 ----
    // Layer-1: D = W1'^T (A) x P (B) -> h1^T C-layout [n=quad*4+r2][j=c],
    // which IS the 16x16x16 B-operand layout -> layer-2 straight from registers.
    #pragma unroll 1
    for (int q8 = 0; q8 < 4; ++q8) {
        const int i = wv + 8 * q8;
        f32x4 acc[2][3];
        #pragma unroll
        for (int Nt = 0; Nt < 3; ++Nt) {
            f32x4 bias = *(const f32x4*)&eb1_s[Nt * 16 + quad * 4];
            acc[0][Nt] = bias;
            acc[1][Nt] = bias;
        }

        #pragma unroll
        for (int Kt = 0; Kt < 8; ++Kt) {
            const int koff = Kt * 32 + quad * 8;
            f16x8 iv  = *(const f16x8*)&xs_h[i * XBP + koff];
            f16x8 jv0 = *(const f16x8*)&xs_h[c * XBP + koff];
            f16x8 jv1 = *(const f16x8*)&xs_h[(16 + c) * XBP + koff];
            f16x8 P0 = iv * jv0;               // B-operand: B[k][j=c]
            f16x8 P1 = iv * jv1;
            #pragma unroll
            for (int Nt = 0; Nt < 3; ++Nt) {
                acc[0][Nt] = __builtin_amdgcn_mfma_f32_16x16x32_f16(b1f[Nt][Kt], P0, acc[0][Nt], 0, 0, 0);
                acc[1][Nt] = __builtin_amdgcn_mfma_f32_16x16x32_f16(b1f[Nt][Kt], P1, acc[1][Nt], 0, 0, 0);
            }
        }

        // epilogue: act -> MFMA16 x3 -> act -> 2-shfl allred -> contract
        const float rix = rs_s[i * 3 + 0], riy = rs_s[i * 3 + 1], riz = rs_s[i * 3 + 2];
        float cxi = 0.f, cyi = 0.f, czi = 0.f;
        const f32x4 b2i = *(const f32x4*)&b2_s[quad * 4];
        #pragma unroll
        for (int h = 0; h < 2; ++h) {
            f32x4 acc2 = b2i;
            #pragma unroll
            for (int Nt = 0; Nt < 3; ++Nt) {
                f16x4 bh;
                #pragma unroll
                for (int r2 = 0; r2 < 4; ++r2)
                    bh[r2] = (_Float16)ssp2(acc[h][Nt][r2]);   // bias pre-folded
                acc2 = MFMA16(b2fT[Nt], bh, acc2);
            }
            float ws = 0.f;
            #pragma unroll
            for (int r2 = 0; r2 < 4; ++r2)
                ws = fmaf(w3q[r2], ssp2(acc2[r2]), ws);
            ws += __shfl_xor(ws, 16);
            ws += __shfl_xor(ws, 32);          // allreduce over m (quads)
            float wj = ws + eb3v;
            int j = c + 16 * h;
            cxi = fmaf(wj, rix - rs_s[j * 3 + 0], cxi);
            cyi = fmaf(wj, riy - rs_s[j * 3 + 1], cyi);
            czi = fmaf(wj, riz - rs_s[j * 3 + 2], czi);
        }
        // reduce over j (c lanes); quads hold identical replicas
        #pragma unroll
        for (int m2 = 1; m2 < 16; m2 <<= 1) {
            cxi += __shfl_xor(cxi, m2);
            cyi += __shfl_xor(cyi, m2);
            czi += __shfl_xor(czi, m2);
        }
        if (l == 0) {
            bfe_s[i * 3 + 0] = cxi;
            bfe_s[i * 3 + 1] = cyi;
            bfe_s[i * 3 + 2] = czi;
        }
    }
    __syncthreads();   // B8: bfe_s (+ bfn_s/cut_s) ready

    // ---- final combine + store (threads 0..95) ----
    if (t < N_ * 3) {
        int i = t / 3;
        out[(size_t)b * (N_ * 3) + t] =
            rs_s[t] + 1e-4f * cut_s[i] * (bfe_s[t] + bfn_s[t]);
    }
}

extern "C" void kernel_launch(void* const* d_in, const int* in_sizes, int n_in,
                              void* d_out, int out_size, void* d_ws, size_t ws_size,
                              hipStream_t stream)
{
    const float* rs     = (const float*)d_in[0];
    const float* xs     = (const float*)d_in[1];
    const float* coords = (const float*)d_in[2];
    const float* ew1    = (const float*)d_in[3];
    const float* eb1    = (const float*)d_in[4];
    const float* ew2    = (const float*)d_in[5];
    const float* eb2    = (const float*)d_in[6];
    const float* ew3    = (const float*)d_in[7];
    const float* eb3    = (const float*)d_in[8];
    const float* nw1    = (const float*)d_in[9];
    const float* nb1    = (const float*)d_in[10];
    const float* nw2    = (const float*)d_in[11];
    const float* nb2    = (const float*)d_in[12];
    const float* nw3    = (const float*)d_in[13];
    const float* nb3    = (const float*)d_in[14];

    k_fused<<<B_, 512, 0, stream>>>(rs, xs, coords, ew1, eb1, ew2, eb2, ew3, eb3,
                                    nw1, nb1, nw2, nb2, nw3, nb3, (float*)d_out);
}